// Round 7
// baseline (355.101 us; speedup 1.0000x reference)
//
#include <hip/hip_runtime.h>
#include <hip/hip_bf16.h>
#include <stdint.h>

typedef unsigned short u16t;
typedef short s8v __attribute__((ext_vector_type(8)));   // 8 bf16 (MFMA A/B frag)
typedef float f32x4 __attribute__((ext_vector_type(4))); // MFMA C/D frag

// ---- constants for this problem ----
#define BB 4
#define SS 2048
#define DD 1024
#define HH 16
#define HD 64
#define MROWS (BB*SS)          // 8192
#define OUT_ELEMS (MROWS*DD)   // 8388608
#define KV_ELEMS (MROWS*DD)    // 8388608 per of k/v

__device__ __forceinline__ u16t f2bf(float f) {
  union { float f; unsigned int u; } v; v.f = f;
  unsigned int u = v.u;
  unsigned int r = (u + 0x7FFFu + ((u >> 16) & 1u)) >> 16;
  return (u16t)r;
}

__device__ __forceinline__ void async_copy16(u16t* lds_dst, const u16t* g_src) {
  __builtin_amdgcn_global_load_lds(
      (const __attribute__((address_space(1))) unsigned int*)(g_src),
      (__attribute__((address_space(3))) unsigned int*)(lds_dst),
      16, 0, 0);
}

// ---------------- conversion kernels ----------------
__global__ void convert_f32_bf16(const float* __restrict__ in, u16t* __restrict__ out) {
  int i = (blockIdx.x * blockDim.x + threadIdx.x) * 4;
  float4 f = *(const float4*)(in + i);
  ushort4 o;
  o.x = f2bf(f.x); o.y = f2bf(f.y); o.z = f2bf(f.z); o.w = f2bf(f.w);
  *(ushort4*)(out + i) = o;
}

// w_proj [K=1024][N=1024] f32 -> WT [N][K] bf16
__global__ void transpose_to_bf16(const float* __restrict__ W, u16t* __restrict__ WT) {
  __shared__ float tile[64][65];
  int bx = blockIdx.x & 15;   // n tile
  int by = blockIdx.x >> 4;   // k tile
  int t = threadIdx.x;
  int c = t & 63, r0 = t >> 6;
  for (int i = 0; i < 16; i++) {
    int r = r0 * 16 + i;
    tile[r][c] = W[(size_t)(by*64 + r)*1024 + bx*64 + c];
  }
  __syncthreads();
  for (int i = 0; i < 16; i++) {
    int r = r0 * 16 + i;
    WT[(size_t)(bx*64 + r)*1024 + by*64 + c] = f2bf(tile[c][r]);
  }
}

// ---------------- GEMM v2: C[M,N] = A[M,K] * B[N,K]^T + bias ----------------
// BK=64, LDS rows of 128B with 16B x (row&7) XOR swizzle (conflict-free
// ds_read_b128; staged via global_load_lds with inverse-swizzled source —
// rule 21 both-sides pattern, verified in attn r6). Tile: 128 x (NF*32),
// 4 waves of 64 x (NF*16). MODE 0: QKV scatter epilogue; MODE 1: f32 out.
template<int MODE, int NF>
__global__ __launch_bounds__(256, 4)
void gemm_bt(const u16t* __restrict__ A, const u16t* __restrict__ Bm,
             const float* __restrict__ bias, float* __restrict__ outF,
             u16t* __restrict__ qb, u16t* __restrict__ kb, u16t* __restrict__ vb,
             float* __restrict__ presK, float* __restrict__ presV,
             int M, int N, int K) {
  __shared__ u16t As[128*64];        // 16KB
  __shared__ u16t Bs[NF*32*64];      // 16KB (NF=4) / 8KB (NF=2)
  const int TN = NF*32;
  int tiles_n = N / TN;
  // bijective XCD swizzle (grid % 8 == 0)
  int cpx = gridDim.x >> 3;
  int wg = (blockIdx.x & 7) * cpx + (blockIdx.x >> 3);
  int bm = wg / tiles_n, bn = wg % tiles_n;
  int t = threadIdx.x;
  int w = t >> 6, l = t & 63;
  int wm = (w >> 1) * 64, wn = (w & 1) * (NF*16);
  int lr = l & 15, lg = l >> 4;
  // staging: linear LDS slot i = r*256 + t -> row = r*32 + (t>>3), chunk = t&7;
  // source chunk = c ^ (row&7)  (involution)
  int Rrow = t >> 3;                                // 0..31
  int csrc = ((t & 7) ^ ((t >> 3) & 7)) * 8;        // u16 offset
  const u16t* Ab = A  + (size_t)(bm * 128) * K;
  const u16t* Bb = Bm + (size_t)(bn * TN) * K;

  f32x4 acc[4][NF] = {};

  for (int k0 = 0; k0 < K; k0 += 64) {
    __syncthreads();
#pragma unroll
    for (int r = 0; r < 4; r++)
      async_copy16(&As[(size_t)(r*256 + t)*8], Ab + (size_t)(r*32 + Rrow)*K + k0 + csrc);
#pragma unroll
    for (int r = 0; r < NF; r++)
      async_copy16(&Bs[(size_t)(r*256 + t)*8], Bb + (size_t)(r*32 + Rrow)*K + k0 + csrc);
    __syncthreads();   // compiler drains vmcnt before barrier
#pragma unroll
    for (int kk = 0; kk < 2; kk++) {
      s8v a[4], b[NF];
#pragma unroll
      for (int mf = 0; mf < 4; mf++) {
        int R = wm + mf*16 + lr;
        a[mf] = *(s8v*)&As[R*64 + (((kk*4 + lg) ^ (R & 7)) << 3)];
      }
#pragma unroll
      for (int nf = 0; nf < NF; nf++) {
        int R = wn + nf*16 + lr;
        b[nf] = *(s8v*)&Bs[R*64 + (((kk*4 + lg) ^ (R & 7)) << 3)];
      }
#pragma unroll
      for (int mf = 0; mf < 4; mf++)
#pragma unroll
        for (int nf = 0; nf < NF; nf++)
          acc[mf][nf] = __builtin_amdgcn_mfma_f32_16x16x32_bf16(a[mf], b[nf], acc[mf][nf], 0, 0, 0);
    }
  }

#pragma unroll
  for (int mf = 0; mf < 4; mf++)
#pragma unroll
    for (int nf = 0; nf < NF; nf++)
#pragma unroll
      for (int j = 0; j < 4; j++) {
        int m = bm*128 + wm + mf*16 + lg*4 + j;
        int n = bn*TN + wn + nf*16 + lr;
        float val = acc[mf][nf][j] + bias[n];
        if (MODE == 1) {
          outF[(size_t)m * N + n] = val;
        } else {
          int part = n >> 10, nn = n & 1023;
          int h = nn >> 6, d = nn & 63;
          int bi = m >> 11, s = m & 2047;
          size_t idx = ((size_t)(bi*HH + h)*SS + s)*HD + d;
          if (part == 0) {
            qb[idx] = f2bf(val * 0.125f);          // fold 1/sqrt(hd) into q
          } else if (part == 1) {
            kb[idx] = f2bf(val); presK[idx] = val;
          } else {
            // V stored TRANSPOSED per head: [B,H,hd,S]
            vb[((size_t)(bi*HH + h)*HD + d)*SS + s] = f2bf(val);
            presV[idx] = val;
          }
        }
      }
}

// ---------------- causal flash attention (swapped-QK, in-register P) -------
__global__ __launch_bounds__(256, 5)
void attn_kernel(const u16t* __restrict__ qb, const u16t* __restrict__ kb,
                 const u16t* __restrict__ vtb, u16t* __restrict__ ab) {
  __shared__ u16t Ks[2][64*64];   // [kv 64][d 64], swizzled, 8KB each
  __shared__ u16t Vs[2][64*64];   // [d 64][kv 64], swizzled

  // XCD-aware remap: each XCD owns 8 heads (K+V = 4MB = its L2)
  int bid = blockIdx.x;
  int logical = (bid & 7) * 256 + (bid >> 3);
  int bh = logical >> 5;
  int qt = 31 - (logical & 31);    // descending q0 within head
  int q0 = qt * 64;
  int t = threadIdx.x, w = t >> 6, l = t & 63;
  int lr = l & 15, lg = l >> 4;
  const u16t* Qg = qb  + (size_t)bh * SS * HD;
  const u16t* Kg = kb  + (size_t)bh * SS * HD;
  const u16t* Vg = vtb + (size_t)bh * HD * SS;   // [hd][S]

  int Rrow = t >> 3;
  int csrc = (((t & 7) ^ ((t >> 3) & 7))) * 8;

  // Q fragments straight from global (pre-scaled by 1/8 in GEMM epilogue)
  s8v qa0 = *(const s8v*)&Qg[(size_t)(q0 + w*16 + lr)*HD + lg*8];
  s8v qa1 = *(const s8v*)&Qg[(size_t)(q0 + w*16 + lr)*HD + 32 + lg*8];

  f32x4 o[4] = {};
  float m_ = -1e30f, l_ = 0.f;       // per-lane online-softmax state, row = lr

  auto swz = [](int R, int c) { return R*64 + ((c ^ (R & 7)) << 3); };

  int nt = qt + 1;
#pragma unroll
  for (int r = 0; r < 2; r++) {
    async_copy16(&Ks[0][(size_t)(r*256 + w*64) * 8], Kg + (size_t)(r*32 + Rrow)*HD + csrc);
    async_copy16(&Vs[0][(size_t)(r*256 + w*64) * 8], Vg + (size_t)(r*32 + Rrow)*SS + csrc);
  }
  __syncthreads();

  int src0 = (l & 15) | ((l & 16) << 1);   // lr + 32*(lg&1)
  int src1 = src0 + 16;
  bool hi = (l & 32) != 0;                 // lg>>1

  int cur = 0;
  for (int tt = 0; tt < nt; tt++) {
    int kv0 = tt * 64;
    if (tt + 1 < nt) {       // stage next tile into other buffer
      int kn = kv0 + 64;
#pragma unroll
      for (int r = 0; r < 2; r++) {
        async_copy16(&Ks[cur^1][(size_t)(r*256 + w*64) * 8], Kg + (size_t)(kn + r*32 + Rrow)*HD + csrc);
        async_copy16(&Vs[cur^1][(size_t)(r*256 + w*64) * 8], Vg + (size_t)(r*32 + Rrow)*SS + kn + csrc);
      }
    }

    const u16t* Kt = Ks[cur];
    const u16t* Vt = Vs[cur];

    // swapped QK^T: S^T frag — lane holds S[q=lr][kv = nf*16 + lg*4 + j]
    f32x4 s[4];
#pragma unroll
    for (int nf = 0; nf < 4; nf++) {
      int R = nf*16 + lr;
      s8v bk0 = *(const s8v*)&Kt[swz(R, lg)];
      s8v bk1 = *(const s8v*)&Kt[swz(R, 4 + lg)];
      f32x4 a = {};
      a = __builtin_amdgcn_mfma_f32_16x16x32_bf16(bk0, qa0, a, 0, 0, 0);
      a = __builtin_amdgcn_mfma_f32_16x16x32_bf16(bk1, qa1, a, 0, 0, 0);
      s[nf] = a;
    }
    if (tt == qt) {  // diagonal tile: causal mask (kv > q)
      int qrow = w*16 + lr;
#pragma unroll
      for (int nf = 0; nf < 4; nf++)
#pragma unroll
        for (int j = 0; j < 4; j++) {
          int kv = nf*16 + lg*4 + j;
          if (kv > qrow) s[nf][j] = -1e30f;
        }
    }

    // row max (row spans lanes lr, lr+16, lr+32, lr+48)
    float pmax = s[0][0];
#pragma unroll
    for (int nf = 0; nf < 4; nf++)
#pragma unroll
      for (int j = 0; j < 4; j++) pmax = fmaxf(pmax, s[nf][j]);
    pmax = fmaxf(pmax, __shfl_xor(pmax, 16));
    pmax = fmaxf(pmax, __shfl_xor(pmax, 32));

    // defer-max (T13): only rescale when some row grew by > 8
    if (!__all(pmax <= m_ + 8.0f)) {
      float mnew = fmaxf(m_, pmax);
      float r_ = __expf(m_ - mnew);
      m_ = mnew;
      l_ *= r_;
      float r0f = __shfl(r_, 4*lg + 0);
      float r1f = __shfl(r_, 4*lg + 1);
      float r2f = __shfl(r_, 4*lg + 2);
      float r3f = __shfl(r_, 4*lg + 3);
#pragma unroll
      for (int nf = 0; nf < 4; nf++) {
        o[nf][0] *= r0f; o[nf][1] *= r1f; o[nf][2] *= r2f; o[nf][3] *= r3f;
      }
    }

    float psum = 0.f;
#pragma unroll
    for (int nf = 0; nf < 4; nf++)
#pragma unroll
      for (int j = 0; j < 4; j++) {
        float p = __expf(s[nf][j] - m_);
        s[nf][j] = p;
        psum += p;
      }
    psum += __shfl_xor(psum, 16);
    psum += __shfl_xor(psum, 32);
    l_ += psum;

    // pack P to bf16 pairs: s01/s23[nf] hold kv = nf*16+lg*4+{0,1}/{2,3}
    uint32_t s01[4], s23[4];
#pragma unroll
    for (int nf = 0; nf < 4; nf++) {
      asm("v_cvt_pk_bf16_f32 %0, %1, %2" : "=v"(s01[nf]) : "v"(s[nf][0]), "v"(s[nf][1]));
      asm("v_cvt_pk_bf16_f32 %0, %1, %2" : "=v"(s23[nf]) : "v"(s[nf][2]), "v"(s[nf][3]));
    }
    // build PV A-frags in-register
    union PU { s8v v; uint32_t w[4]; } pa0, pa1;
    {
      uint32_t t00 = __shfl(s01[0], src0), t01 = __shfl(s01[1], src0);
      uint32_t t10 = __shfl(s23[0], src0), t11 = __shfl(s23[1], src0);
      uint32_t t20 = __shfl(s01[0], src1), t21 = __shfl(s01[1], src1);
      uint32_t t30 = __shfl(s23[0], src1), t31 = __shfl(s23[1], src1);
      pa0.w[0] = hi ? t01 : t00; pa0.w[1] = hi ? t11 : t10;
      pa0.w[2] = hi ? t21 : t20; pa0.w[3] = hi ? t31 : t30;
      uint32_t u00 = __shfl(s01[2], src0), u01 = __shfl(s01[3], src0);
      uint32_t u10 = __shfl(s23[2], src0), u11 = __shfl(s23[3], src0);
      uint32_t u20 = __shfl(s01[2], src1), u21 = __shfl(s01[3], src1);
      uint32_t u30 = __shfl(s23[2], src1), u31 = __shfl(s23[3], src1);
      pa1.w[0] = hi ? u01 : u00; pa1.w[1] = hi ? u11 : u10;
      pa1.w[2] = hi ? u21 : u20; pa1.w[3] = hi ? u31 : u30;
    }

#pragma unroll
    for (int nf = 0; nf < 4; nf++) {
      int R = nf*16 + lr;
      s8v vv0 = *(const s8v*)&Vt[swz(R, lg)];
      s8v vv1 = *(const s8v*)&Vt[swz(R, 4 + lg)];
      o[nf] = __builtin_amdgcn_mfma_f32_16x16x32_bf16(pa0.v, vv0, o[nf], 0, 0, 0);
      o[nf] = __builtin_amdgcn_mfma_f32_16x16x32_bf16(pa1.v, vv1, o[nf], 0, 0, 0);
    }

    __syncthreads();   // drains vmcnt (next tile landed) + protects buffers
    cur ^= 1;
  }

  // transpose 1/l to C-layout rows and write out
  float li0 = 1.f / __shfl(l_, 4*lg + 0);
  float li1 = 1.f / __shfl(l_, 4*lg + 1);
  float li2 = 1.f / __shfl(l_, 4*lg + 2);
  float li3 = 1.f / __shfl(l_, 4*lg + 3);
  int bi = bh >> 4, h = bh & 15;
#pragma unroll
  for (int nf = 0; nf < 4; nf++) {
    int row = q0 + w*16 + lg*4;
    int col = h*HD + nf*16 + lr;
    ab[((size_t)bi*SS + row + 0)*DD + col] = f2bf(o[nf][0] * li0);
    ab[((size_t)bi*SS + row + 1)*DD + col] = f2bf(o[nf][1] * li1);
    ab[((size_t)bi*SS + row + 2)*DD + col] = f2bf(o[nf][2] * li2);
    ab[((size_t)bi*SS + row + 3)*DD + col] = f2bf(o[nf][3] * li3);
  }
}

extern "C" void kernel_launch(void* const* d_in, const int* in_sizes, int n_in,
                              void* d_out, int out_size, void* d_ws, size_t ws_size,
                              hipStream_t stream) {
  const float* x      = (const float*)d_in[0];
  const float* w_attn = (const float*)d_in[1];
  const float* b_attn = (const float*)d_in[2];
  const float* w_proj = (const float*)d_in[3];
  const float* b_proj = (const float*)d_in[4];
  float* out   = (float*)d_out;
  float* presK = out + (size_t)OUT_ELEMS;
  float* presV = presK + (size_t)KV_ELEMS;

  u16t* ws    = (u16t*)d_ws;
  u16t* x_bf  = ws;                        // 8388608 elems
  u16t* wa_bf = x_bf  + (size_t)OUT_ELEMS; // 3145728
  u16t* wpT   = wa_bf + 3145728;           // 1048576
  u16t* q_bf  = wpT   + 1048576;           // 8388608
  u16t* k_bf  = q_bf  + (size_t)KV_ELEMS;
  u16t* vt_bf = k_bf  + (size_t)KV_ELEMS;  // [B,H,hd,S]
  u16t* a_bf  = x_bf;                      // reuse x_bf after QKV GEMM

  convert_f32_bf16<<<8192, 256, 0, stream>>>(x, x_bf);
  convert_f32_bf16<<<3072, 256, 0, stream>>>(w_attn, wa_bf);
  transpose_to_bf16<<<256, 256, 0, stream>>>(w_proj, wpT);

  gemm_bt<0,4><<<64*24, 256, 0, stream>>>(x_bf, wa_bf, b_attn, nullptr,
                                          q_bf, k_bf, vt_bf, presK, presV,
                                          MROWS, 3*DD, DD);
  attn_kernel<<<64*32, 256, 0, stream>>>(q_bf, k_bf, vt_bf, a_bf);
  gemm_bt<1,2><<<128*8, 256, 0, stream>>>(a_bf, wpT, b_proj, out,
                                          nullptr, nullptr, nullptr, nullptr, nullptr,
                                          MROWS, DD, DD);
}

// Round 9
// 344.641 us; speedup vs baseline: 1.0303x; 1.0303x over previous
//
#include <hip/hip_runtime.h>
#include <hip/hip_bf16.h>
#include <stdint.h>

typedef unsigned short u16t;
typedef short s8v __attribute__((ext_vector_type(8)));   // 8 bf16 (MFMA A/B frag)
typedef float f32x4 __attribute__((ext_vector_type(4))); // MFMA C/D frag

// ---- constants for this problem ----
#define BB 4
#define SS 2048
#define DD 1024
#define HH 16
#define HD 64
#define MROWS (BB*SS)          // 8192
#define OUT_ELEMS (MROWS*DD)   // 8388608
#define KV_ELEMS (MROWS*DD)    // 8388608 per of k/v

__device__ __forceinline__ u16t f2bf(float f) {
  union { float f; unsigned int u; } v; v.f = f;
  unsigned int u = v.u;
  unsigned int r = (u + 0x7FFFu + ((u >> 16) & 1u)) >> 16;
  return (u16t)r;
}

__device__ __forceinline__ void async_copy16(u16t* lds_dst, const u16t* g_src) {
  __builtin_amdgcn_global_load_lds(
      (const __attribute__((address_space(1))) unsigned int*)(g_src),
      (__attribute__((address_space(3))) unsigned int*)(lds_dst),
      16, 0, 0);
}

// ---------------- conversion kernels ----------------
__global__ void convert_f32_bf16(const float* __restrict__ in, u16t* __restrict__ out) {
  int i = (blockIdx.x * blockDim.x + threadIdx.x) * 4;
  float4 f = *(const float4*)(in + i);
  ushort4 o;
  o.x = f2bf(f.x); o.y = f2bf(f.y); o.z = f2bf(f.z); o.w = f2bf(f.w);
  *(ushort4*)(out + i) = o;
}

// w_proj [K=1024][N=1024] f32 -> WT [N][K] bf16
__global__ void transpose_to_bf16(const float* __restrict__ W, u16t* __restrict__ WT) {
  __shared__ float tile[64][65];
  int bx = blockIdx.x & 15;   // n tile
  int by = blockIdx.x >> 4;   // k tile
  int t = threadIdx.x;
  int c = t & 63, r0 = t >> 6;
  for (int i = 0; i < 16; i++) {
    int r = r0 * 16 + i;
    tile[r][c] = W[(size_t)(by*64 + r)*1024 + bx*64 + c];
  }
  __syncthreads();
  for (int i = 0; i < 16; i++) {
    int r = r0 * 16 + i;
    WT[(size_t)(bx*64 + r)*1024 + by*64 + c] = f2bf(tile[c][r]);
  }
}

// ---------------- GEMM v3: C[M,N] = A[M,K] * B[N,K]^T + bias ----------------
// BK=64 + conflict-free 16B x (row&7) XOR swizzle (r7-verified, conflicts=0)
// + double-buffered prefetch (attn-verified): stage tile t+1 via
// global_load_lds BEFORE computing tile t; ONE __syncthreads per K-step
// (drains vmcnt -> prefetch landed; protects the buffer being overwritten).
// Tile 128 x (NF*32), 4 waves of 64 x (NF*16). LDS = 64KB (NF=4) -> 2
// blocks/CU; prefetch overlap replaces occupancy as the latency hider.
template<int MODE, int NF>
__global__ __launch_bounds__(256, 2)
void gemm_bt(const u16t* __restrict__ A, const u16t* __restrict__ Bm,
             const float* __restrict__ bias, float* __restrict__ outF,
             u16t* __restrict__ qb, u16t* __restrict__ kb, u16t* __restrict__ vb,
             float* __restrict__ presK, float* __restrict__ presV,
             int M, int N, int K) {
  __shared__ u16t As[2][128*64];     // 16KB each
  __shared__ u16t Bs[2][NF*32*64];   // 16KB each (NF=4)
  const int TN = NF*32;
  int tiles_n = N / TN;
  // bijective XCD swizzle (grid % 8 == 0)
  int cpx = gridDim.x >> 3;
  int wg = (blockIdx.x & 7) * cpx + (blockIdx.x >> 3);
  int bm = wg / tiles_n, bn = wg % tiles_n;
  int t = threadIdx.x;
  int w = t >> 6, l = t & 63;
  int wm = (w >> 1) * 64, wn = (w & 1) * (NF*16);
  int lr = l & 15, lg = l >> 4;
  // staging: linear LDS slot i = r*256 + t -> row = r*32 + (t>>3), chunk = t&7;
  // source chunk = chunk ^ (row&7)  (involution; r*32 ≡ 0 mod 8)
  int Rrow = t >> 3;                                // 0..31
  int csrc = ((t & 7) ^ ((t >> 3) & 7)) * 8;        // u16 offset
  const u16t* Ab = A  + (size_t)(bm * 128) * K;
  const u16t* Bb = Bm + (size_t)(bn * TN) * K;

  f32x4 acc[4][NF] = {};

  // prologue: stage K-tile 0 into buffer 0
#pragma unroll
  for (int r = 0; r < 4; r++)
    async_copy16(&As[0][(size_t)(r*256 + t)*8], Ab + (size_t)(r*32 + Rrow)*K + csrc);
#pragma unroll
  for (int r = 0; r < NF; r++)
    async_copy16(&Bs[0][(size_t)(r*256 + t)*8], Bb + (size_t)(r*32 + Rrow)*K + csrc);
  __syncthreads();

  int cur = 0;
  for (int k0 = 0; k0 < K; k0 += 64) {
    if (k0 + 64 < K) {     // prefetch next K-tile into other buffer
#pragma unroll
      for (int r = 0; r < 4; r++)
        async_copy16(&As[cur^1][(size_t)(r*256 + t)*8], Ab + (size_t)(r*32 + Rrow)*K + k0 + 64 + csrc);
#pragma unroll
      for (int r = 0; r < NF; r++)
        async_copy16(&Bs[cur^1][(size_t)(r*256 + t)*8], Bb + (size_t)(r*32 + Rrow)*K + k0 + 64 + csrc);
    }
#pragma unroll
    for (int kk = 0; kk < 2; kk++) {
      s8v a[4], b[NF];
#pragma unroll
      for (int mf = 0; mf < 4; mf++) {
        int R = wm + mf*16 + lr;
        a[mf] = *(s8v*)&As[cur][R*64 + (((kk*4 + lg) ^ (R & 7)) << 3)];
      }
#pragma unroll
      for (int nf = 0; nf < NF; nf++) {
        int R = wn + nf*16 + lr;
        b[nf] = *(s8v*)&Bs[cur][R*64 + (((kk*4 + lg) ^ (R & 7)) << 3)];
      }
#pragma unroll
      for (int mf = 0; mf < 4; mf++)
#pragma unroll
        for (int nf = 0; nf < NF; nf++)
          acc[mf][nf] = __builtin_amdgcn_mfma_f32_16x16x32_bf16(a[mf], b[nf], acc[mf][nf], 0, 0, 0);
    }
    __syncthreads();   // drains vmcnt (prefetch landed) + protects read buffer
    cur ^= 1;
  }

#pragma unroll
  for (int mf = 0; mf < 4; mf++)
#pragma unroll
    for (int nf = 0; nf < NF; nf++)
#pragma unroll
      for (int j = 0; j < 4; j++) {
        int m = bm*128 + wm + mf*16 + lg*4 + j;
        int n = bn*TN + wn + nf*16 + lr;
        float val = acc[mf][nf][j] + bias[n];
        if (MODE == 1) {
          outF[(size_t)m * N + n] = val;
        } else {
          int part = n >> 10, nn = n & 1023;
          int h = nn >> 6, d = nn & 63;
          int bi = m >> 11, s = m & 2047;
          size_t idx = ((size_t)(bi*HH + h)*SS + s)*HD + d;
          if (part == 0) {
            qb[idx] = f2bf(val * 0.125f);          // fold 1/sqrt(hd) into q
          } else if (part == 1) {
            kb[idx] = f2bf(val); presK[idx] = val;
          } else {
            // V stored TRANSPOSED per head: [B,H,hd,S]
            vb[((size_t)(bi*HH + h)*HD + d)*SS + s] = f2bf(val);
            presV[idx] = val;
          }
        }
      }
}

// ---------------- causal flash attention (swapped-QK, in-register P) -------
__global__ __launch_bounds__(256, 5)
void attn_kernel(const u16t* __restrict__ qb, const u16t* __restrict__ kb,
                 const u16t* __restrict__ vtb, u16t* __restrict__ ab) {
  __shared__ u16t Ks[2][64*64];   // [kv 64][d 64], swizzled, 8KB each
  __shared__ u16t Vs[2][64*64];   // [d 64][kv 64], swizzled

  // XCD-aware remap: each XCD owns 8 heads (K+V = 4MB = its L2)
  int bid = blockIdx.x;
  int logical = (bid & 7) * 256 + (bid >> 3);
  int bh = logical >> 5;
  int qt = 31 - (logical & 31);    // descending q0 within head
  int q0 = qt * 64;
  int t = threadIdx.x, w = t >> 6, l = t & 63;
  int lr = l & 15, lg = l >> 4;
  const u16t* Qg = qb  + (size_t)bh * SS * HD;
  const u16t* Kg = kb  + (size_t)bh * SS * HD;
  const u16t* Vg = vtb + (size_t)bh * HD * SS;   // [hd][S]

  int Rrow = t >> 3;
  int csrc = (((t & 7) ^ ((t >> 3) & 7))) * 8;

  // Q fragments straight from global (pre-scaled by 1/8 in GEMM epilogue)
  s8v qa0 = *(const s8v*)&Qg[(size_t)(q0 + w*16 + lr)*HD + lg*8];
  s8v qa1 = *(const s8v*)&Qg[(size_t)(q0 + w*16 + lr)*HD + 32 + lg*8];

  f32x4 o[4] = {};
  float m_ = -1e30f, l_ = 0.f;       // per-lane online-softmax state, row = lr

  auto swz = [](int R, int c) { return R*64 + ((c ^ (R & 7)) << 3); };

  int nt = qt + 1;
#pragma unroll
  for (int r = 0; r < 2; r++) {
    async_copy16(&Ks[0][(size_t)(r*256 + w*64) * 8], Kg + (size_t)(r*32 + Rrow)*HD + csrc);
    async_copy16(&Vs[0][(size_t)(r*256 + w*64) * 8], Vg + (size_t)(r*32 + Rrow)*SS + csrc);
  }
  __syncthreads();

  int src0 = (l & 15) | ((l & 16) << 1);   // lr + 32*(lg&1)
  int src1 = src0 + 16;
  bool hi = (l & 32) != 0;                 // lg>>1

  int cur = 0;
  for (int tt = 0; tt < nt; tt++) {
    int kv0 = tt * 64;
    if (tt + 1 < nt) {       // stage next tile into other buffer
      int kn = kv0 + 64;
#pragma unroll
      for (int r = 0; r < 2; r++) {
        async_copy16(&Ks[cur^1][(size_t)(r*256 + w*64) * 8], Kg + (size_t)(kn + r*32 + Rrow)*HD + csrc);
        async_copy16(&Vs[cur^1][(size_t)(r*256 + w*64) * 8], Vg + (size_t)(r*32 + Rrow)*SS + kn + csrc);
      }
    }

    const u16t* Kt = Ks[cur];
    const u16t* Vt = Vs[cur];

    // swapped QK^T: S^T frag — lane holds S[q=lr][kv = nf*16 + lg*4 + j]
    f32x4 s[4];
#pragma unroll
    for (int nf = 0; nf < 4; nf++) {
      int R = nf*16 + lr;
      s8v bk0 = *(const s8v*)&Kt[swz(R, lg)];
      s8v bk1 = *(const s8v*)&Kt[swz(R, 4 + lg)];
      f32x4 a = {};
      a = __builtin_amdgcn_mfma_f32_16x16x32_bf16(bk0, qa0, a, 0, 0, 0);
      a = __builtin_amdgcn_mfma_f32_16x16x32_bf16(bk1, qa1, a, 0, 0, 0);
      s[nf] = a;
    }
    if (tt == qt) {  // diagonal tile: causal mask (kv > q)
      int qrow = w*16 + lr;
#pragma unroll
      for (int nf = 0; nf < 4; nf++)
#pragma unroll
        for (int j = 0; j < 4; j++) {
          int kv = nf*16 + lg*4 + j;
          if (kv > qrow) s[nf][j] = -1e30f;
        }
    }

    // row max (row spans lanes lr, lr+16, lr+32, lr+48)
    float pmax = s[0][0];
#pragma unroll
    for (int nf = 0; nf < 4; nf++)
#pragma unroll
      for (int j = 0; j < 4; j++) pmax = fmaxf(pmax, s[nf][j]);
    pmax = fmaxf(pmax, __shfl_xor(pmax, 16));
    pmax = fmaxf(pmax, __shfl_xor(pmax, 32));

    // defer-max (T13): only rescale when some row grew by > 8
    if (!__all(pmax <= m_ + 8.0f)) {
      float mnew = fmaxf(m_, pmax);
      float r_ = __expf(m_ - mnew);
      m_ = mnew;
      l_ *= r_;
      float r0f = __shfl(r_, 4*lg + 0);
      float r1f = __shfl(r_, 4*lg + 1);
      float r2f = __shfl(r_, 4*lg + 2);
      float r3f = __shfl(r_, 4*lg + 3);
#pragma unroll
      for (int nf = 0; nf < 4; nf++) {
        o[nf][0] *= r0f; o[nf][1] *= r1f; o[nf][2] *= r2f; o[nf][3] *= r3f;
      }
    }

    float psum = 0.f;
#pragma unroll
    for (int nf = 0; nf < 4; nf++)
#pragma unroll
      for (int j = 0; j < 4; j++) {
        float p = __expf(s[nf][j] - m_);
        s[nf][j] = p;
        psum += p;
      }
    psum += __shfl_xor(psum, 16);
    psum += __shfl_xor(psum, 32);
    l_ += psum;

    // pack P to bf16 pairs: s01/s23[nf] hold kv = nf*16+lg*4+{0,1}/{2,3}
    uint32_t s01[4], s23[4];
#pragma unroll
    for (int nf = 0; nf < 4; nf++) {
      asm("v_cvt_pk_bf16_f32 %0, %1, %2" : "=v"(s01[nf]) : "v"(s[nf][0]), "v"(s[nf][1]));
      asm("v_cvt_pk_bf16_f32 %0, %1, %2" : "=v"(s23[nf]) : "v"(s[nf][2]), "v"(s[nf][3]));
    }
    // build PV A-frags in-register
    union PU { s8v v; uint32_t w[4]; } pa0, pa1;
    {
      uint32_t t00 = __shfl(s01[0], src0), t01 = __shfl(s01[1], src0);
      uint32_t t10 = __shfl(s23[0], src0), t11 = __shfl(s23[1], src0);
      uint32_t t20 = __shfl(s01[0], src1), t21 = __shfl(s01[1], src1);
      uint32_t t30 = __shfl(s23[0], src1), t31 = __shfl(s23[1], src1);
      pa0.w[0] = hi ? t01 : t00; pa0.w[1] = hi ? t11 : t10;
      pa0.w[2] = hi ? t21 : t20; pa0.w[3] = hi ? t31 : t30;
      uint32_t u00 = __shfl(s01[2], src0), u01 = __shfl(s01[3], src0);
      uint32_t u10 = __shfl(s23[2], src0), u11 = __shfl(s23[3], src0);
      uint32_t u20 = __shfl(s01[2], src1), u21 = __shfl(s01[3], src1);
      uint32_t u30 = __shfl(s23[2], src1), u31 = __shfl(s23[3], src1);
      pa1.w[0] = hi ? u01 : u00; pa1.w[1] = hi ? u11 : u10;
      pa1.w[2] = hi ? u21 : u20; pa1.w[3] = hi ? u31 : u30;
    }

#pragma unroll
    for (int nf = 0; nf < 4; nf++) {
      int R = nf*16 + lr;
      s8v vv0 = *(const s8v*)&Vt[swz(R, lg)];
      s8v vv1 = *(const s8v*)&Vt[swz(R, 4 + lg)];
      o[nf] = __builtin_amdgcn_mfma_f32_16x16x32_bf16(pa0.v, vv0, o[nf], 0, 0, 0);
      o[nf] = __builtin_amdgcn_mfma_f32_16x16x32_bf16(pa1.v, vv1, o[nf], 0, 0, 0);
    }

    __syncthreads();   // drains vmcnt (next tile landed) + protects buffers
    cur ^= 1;
  }

  // transpose 1/l to C-layout rows and write out
  float li0 = 1.f / __shfl(l_, 4*lg + 0);
  float li1 = 1.f / __shfl(l_, 4*lg + 1);
  float li2 = 1.f / __shfl(l_, 4*lg + 2);
  float li3 = 1.f / __shfl(l_, 4*lg + 3);
  int bi = bh >> 4, h = bh & 15;
#pragma unroll
  for (int nf = 0; nf < 4; nf++) {
    int row = q0 + w*16 + lg*4;
    int col = h*HD + nf*16 + lr;
    ab[((size_t)bi*SS + row + 0)*DD + col] = f2bf(o[nf][0] * li0);
    ab[((size_t)bi*SS + row + 1)*DD + col] = f2bf(o[nf][1] * li1);
    ab[((size_t)bi*SS + row + 2)*DD + col] = f2bf(o[nf][2] * li2);
    ab[((size_t)bi*SS + row + 3)*DD + col] = f2bf(o[nf][3] * li3);
  }
}

extern "C" void kernel_launch(void* const* d_in, const int* in_sizes, int n_in,
                              void* d_out, int out_size, void* d_ws, size_t ws_size,
                              hipStream_t stream) {
  const float* x      = (const float*)d_in[0];
  const float* w_attn = (const float*)d_in[1];
  const float* b_attn = (const float*)d_in[2];
  const float* w_proj = (const float*)d_in[3];
  const float* b_proj = (const float*)d_in[4];
  float* out   = (float*)d_out;
  float* presK = out + (size_t)OUT_ELEMS;
  float* presV = presK + (size_t)KV_ELEMS;

  u16t* ws    = (u16t*)d_ws;
  u16t* x_bf  = ws;                        // 8388608 elems
  u16t* wa_bf = x_bf  + (size_t)OUT_ELEMS; // 3145728
  u16t* wpT   = wa_bf + 3145728;           // 1048576
  u16t* q_bf  = wpT   + 1048576;           // 8388608
  u16t* k_bf  = q_bf  + (size_t)KV_ELEMS;
  u16t* vt_bf = k_bf  + (size_t)KV_ELEMS;  // [B,H,hd,S]
  u16t* a_bf  = x_bf;                      // reuse x_bf after QKV GEMM

  convert_f32_bf16<<<8192, 256, 0, stream>>>(x, x_bf);
  convert_f32_bf16<<<3072, 256, 0, stream>>>(w_attn, wa_bf);
  transpose_to_bf16<<<256, 256, 0, stream>>>(w_proj, wpT);

  gemm_bt<0,4><<<64*24, 256, 0, stream>>>(x_bf, wa_bf, b_attn, nullptr,
                                          q_bf, k_bf, vt_bf, presK, presV,
                                          MROWS, 3*DD, DD);
  attn_kernel<<<64*32, 256, 0, stream>>>(q_bf, k_bf, vt_bf, a_bf);
  gemm_bt<1,4><<<64*8, 256, 0, stream>>>(a_bf, wpT, b_proj, out,
                                         nullptr, nullptr, nullptr, nullptr, nullptr,
                                         MROWS, DD, DD);
}